// Round 10
// baseline (402.684 us; speedup 1.0000x reference)
//
#include <hip/hip_runtime.h>
#include <math.h>

// Problem constants
#define B_    32
#define L_    4096
#define CIN_  128
#define H_    256
#define T_    4094          // L - K + 1
#define KTOT_ 384           // CIN * K

#define MT_   64            // timesteps per tile (M tile)
#define NTB_  64            // t-tiles (64 * 64 = 4096)
#define NKT_  12            // K-steps of 32
#define TPB_  4             // tiles per persistent block (grid 512)

typedef float f32x4 __attribute__((ext_vector_type(4)));
typedef short s16x8 __attribute__((ext_vector_type(8)));

static __device__ __forceinline__ unsigned short f2bf(float f) {
  unsigned u = __builtin_bit_cast(unsigned, f);
  u = (u + 0x7FFFu + ((u >> 16) & 1u)) >> 16;
  return (unsigned short)u;
}

// ---------------------------------------------------------------------------
// Kernel 0: pack W (oc,i,k) fp32 -> bf16 [kt 12][kgrp 4][c 768][e 8], with the
// 768 columns GATE-INTERLEAVED: c -> q=c>>4, lr=c&15; gate=q%3, hgrp=q/3;
// oc = gate*256 + hgrp*16 + lr.  Wave wn fragment nj = gate nj for h=wn*16+lr
// -> fo-pool scan runs entirely in registers.
// ---------------------------------------------------------------------------
__global__ __launch_bounds__(256) void packW_bf16(const float* __restrict__ W,
                                                  unsigned short* __restrict__ Wb) {
  const int idx = blockIdx.x * 256 + threadIdx.x;     // 36864 = 144*256
  const int c = idx % 768;
  const int t = idx / 768;
  const int kgrp = t & 3;
  const int kt = t >> 2;                              // 0..11
  const int q = c >> 4, lr = c & 15;
  const int gate = q % 3, hgrp = q / 3;
  const int oc = gate * 256 + hgrp * 16 + lr;
  s16x8 outv;
#pragma unroll
  for (int e = 0; e < 8; ++e) {
    const int kk = kt * 32 + kgrp * 8 + e;
    const int i = kk & 127, k = kk >> 7;
    outv[e] = (short)f2bf(W[(size_t)oc * KTOT_ + i * 3 + k]);
  }
  *(s16x8*)(Wb + (size_t)idx * 8) = outv;
}

// ---------------------------------------------------------------------------
// Kernel 1: PERSISTENT fused bf16-MFMA conv + in-register fo-pool scan.
// grid 512; block p owns batch bb=p&31 and tiles tblk = (p>>5) + 16j, j=0..3.
// block 1024 (16 waves = 1M x 16N); per tile M=64 x N=768 x K=384.
// x staging double-buffered: next tile's loads issued BEFORE current GEMM
// (latency hides under compute); cvt+ds_write after; ONE barrier per tile.
// ---------------------------------------------------------------------------
__global__ __launch_bounds__(1024, 4) void conv_scan_mfma(
    const float* __restrict__ x, const unsigned short* __restrict__ Wb,
    const float* __restrict__ bias, float* __restrict__ Pc,
    float* __restrict__ Sc) {
  // two xs buffers: 66 rows x 128 bf16 (256B pitch, XOR-swizzled) = 2x16896 B
  __shared__ __align__(16) char smem[2 * 66 * 256];

  const int tid = threadIdx.x;
  const int wn = tid >> 6;             // wave 0..15 -> h group [16*wn, 16*wn+16)
  const int l = tid & 63;
  const int lr = l & 15;
  const int lg = l >> 4;
  const int p = blockIdx.x;            // 0..511
  const int bb = p & 31;               // constant across j (512 ≡ 0 mod 32)
  const int tblk0 = p >> 5;            // 0..15

  const float* xb = x + (size_t)bb * L_ * CIN_;

  // per-lane W base: (kt=0, kgrp=lg, c = wn*48 + nj*16 + lr, e=0)
  const unsigned short* bp = Wb + lg * 6144 + (wn * 48 + lr) * 8;

  s16x8 bcur[3];
#pragma unroll
  for (int nj = 0; nj < 3; ++nj)
    bcur[nj] = *(const s16x8*)(bp + nj * 128);

  const int hl = wn * 16 + lr;
  const float bz = bias[hl];
  const float bf_ = bias[256 + hl];
  const float bo_ = bias[512 + hl];

  // ---- prologue: stage tile 0 into buffer 0 ----
  char* cur = smem;
  char* nxt = smem + 66 * 256;
  {
    const int t0 = tblk0 * MT_;
#pragma unroll
    for (int s = 0; s < 3; ++s) {
      const int v = tid + 1024 * s;
      if (v < 66 * 32) {
        const int row = v >> 5;
        int r = t0 + row;
        if (r > L_ - 1) r = L_ - 1;
        const float4 xv = *(const float4*)&xb[(size_t)r * CIN_ + (v & 31) * 4];
        unsigned p0, p1;
        asm("v_cvt_pk_bf16_f32 %0, %1, %2" : "=v"(p0) : "v"(xv.x), "v"(xv.y));
        asm("v_cvt_pk_bf16_f32 %0, %1, %2" : "=v"(p1) : "v"(xv.z), "v"(xv.w));
        *(uint2*)(cur + row * 256 + (((v & 31) * 8) ^ ((row & 7) << 4))) = make_uint2(p0, p1);
      }
    }
  }
  __syncthreads();

  // ---- persistent tile loop ----
  for (int j = 0; j < TPB_; ++j) {
    const int tblk = tblk0 + 16 * j;
    const int t0 = tblk * MT_;
    const bool hn = (j + 1 < TPB_);

    // issue next tile's x loads NOW (consumed after GEMM -> latency hidden)
    float4 xr[3];
    if (hn) {
      const int t0n = (tblk + 16) * MT_;
#pragma unroll
      for (int s = 0; s < 3; ++s) {
        const int v = tid + 1024 * s;
        if (v < 66 * 32) {
          int r = t0n + (v >> 5);
          if (r > L_ - 1) r = L_ - 1;
          xr[s] = *(const float4*)&xb[(size_t)r * CIN_ + (v & 31) * 4];
        }
      }
    }

    // ---- GEMM: M=64 x N=768 x K=384; barrier-free; 1-deep B prefetch ----
    f32x4 acc[4][3];
#pragma unroll
    for (int mi = 0; mi < 4; ++mi)
#pragma unroll
      for (int nj = 0; nj < 3; ++nj) acc[mi][nj] = (f32x4)0.f;

#pragma unroll
    for (int kt = 0; kt < NKT_; ++kt) {
      s16x8 bnxt[3];
      const int ktn = (kt + 1) % NKT_;           // wraps to 0 -> ready for next tile
#pragma unroll
      for (int nj = 0; nj < 3; ++nj)
        bnxt[nj] = *(const s16x8*)(bp + ktn * 24576 + nj * 128);
      const int kof = kt >> 2;                   // conv tap 0..2
      const int cb = (kt & 3) * 64 + lg * 16;    // byte col in xs row
      s16x8 a[4];
#pragma unroll
      for (int mi = 0; mi < 4; ++mi) {
        const int row = mi * 16 + lr + kof;
        a[mi] = *(const s16x8*)(cur + row * 256 + (cb ^ ((row & 7) << 4)));
      }
#pragma unroll
      for (int mi = 0; mi < 4; ++mi)
#pragma unroll
        for (int nj = 0; nj < 3; ++nj)
          acc[mi][nj] = __builtin_amdgcn_mfma_f32_16x16x32_bf16(a[mi], bcur[nj], acc[mi][nj], 0, 0, 0);
#pragma unroll
      for (int nj = 0; nj < 3; ++nj) bcur[nj] = bnxt[nj];
    }

    // ---- in-register fo-pool scan (lane: z,f,o for h=hl at rows mi*16+lg*4+r) ----
    float Pw = 1.f, Sw = 0.f;
#pragma unroll
    for (int mi = 0; mi < 4; ++mi) {
      float Pr = 1.f, Sr = 0.f;
#pragma unroll
      for (int r = 0; r < 4; ++r) {
        const int t = t0 + mi * 16 + lg * 4 + r;
        const float zr = acc[mi][0][r] + bz;
        const float fr = acc[mi][1][r] + bf_;
        const float orr = acc[mi][2][r] + bo_;
        const float zc = fminf(fmaxf(zr, -15.f), 15.f);
        const float e2 = __expf(2.f * zc);
        const float zt = (e2 - 1.f) * __builtin_amdgcn_rcpf(e2 + 1.f);
        const float ft = __builtin_amdgcn_rcpf(1.f + __expf(-fr));
        const float ot = __builtin_amdgcn_rcpf(1.f + __expf(-orr));
        float A = ot * ft;
        float Bv = ot * (1.f - ft) * zt;
        const bool valid = (t < T_);
        A = valid ? A : 1.f;                     // identity for padded steps
        Bv = valid ? Bv : 0.f;
        Sr = A * Sr + Bv;
        Pr = A * Pr;
      }
      // compose across lg (t-stride 4)
      float Pp = __shfl_xor(Pr, 16), Sp = __shfl_xor(Sr, 16);
      if (lg & 1) { Sr = Pr * Sp + Sr; Pr = Pr * Pp; }
      else        { Sr = Pp * Sr + Sp; Pr = Pp * Pr; }
      Pp = __shfl_xor(Pr, 32); Sp = __shfl_xor(Sr, 32);
      if (lg & 2) { Sr = Pr * Sp + Sr; Pr = Pr * Pp; }
      else        { Sr = Pp * Sr + Sp; Pr = Pp * Pr; }
      Sw = Pr * Sw + Sr;
      Pw = Pr * Pw;
    }
    if (lg == 0) {
      const size_t o = ((size_t)bb * NTB_ + tblk) * H_ + hl;
      Pc[o] = Pw;
      Sc[o] = Sw;
    }

    // ---- write next tile into the other buffer, then barrier & swap ----
    if (hn) {
#pragma unroll
      for (int s = 0; s < 3; ++s) {
        const int v = tid + 1024 * s;
        if (v < 66 * 32) {
          const int row = v >> 5;
          unsigned p0, p1;
          asm("v_cvt_pk_bf16_f32 %0, %1, %2" : "=v"(p0) : "v"(xr[s].x), "v"(xr[s].y));
          asm("v_cvt_pk_bf16_f32 %0, %1, %2" : "=v"(p1) : "v"(xr[s].z), "v"(xr[s].w));
          *(uint2*)(nxt + row * 256 + (((v & 31) * 8) ^ ((row & 7) << 4))) = make_uint2(p0, p1);
        }
      }
    }
    __syncthreads();
    char* tmp = cur; cur = nxt; nxt = tmp;
  }
}

// ---------------------------------------------------------------------------
// Kernel 2: compose the 64 tile-affine maps per (b,h) -> final h_T
// ---------------------------------------------------------------------------
__global__ __launch_bounds__(128) void combine_kernel(const float* __restrict__ Pc,
                                                      const float* __restrict__ Sc,
                                                      float* __restrict__ out) {
  const int idx = blockIdx.x * 128 + threadIdx.x;  // 8192 = B*H
  const int b = idx >> 8;
  const int h = idx & 255;
  float hv = 0.f;
#pragma unroll 8
  for (int c = 0; c < NTB_; ++c) {
    const float p = Pc[((size_t)b * NTB_ + c) * H_ + h];
    const float s = Sc[((size_t)b * NTB_ + c) * H_ + h];
    hv = p * hv + s;
  }
  out[idx] = hv;
}

// ---------------------------------------------------------------------------
extern "C" void kernel_launch(void* const* d_in, const int* in_sizes, int n_in,
                              void* d_out, int out_size, void* d_ws, size_t ws_size,
                              hipStream_t stream) {
  const float* x = (const float*)d_in[0];
  const float* W = (const float*)d_in[1];
  const float* bias = (const float*)d_in[2];
  float* out = (float*)d_out;

  char* ws = (char*)d_ws;
  unsigned short* Wb = (unsigned short*)ws;        // 576 KB
  float* Pc = (float*)(ws + (1 << 20));            // 2 MB (32*64*256 f32)
  float* Sc = (float*)(ws + 3 * (1 << 20));        // 2 MB

  packW_bf16<<<144, 256, 0, stream>>>(W, Wb);
  conv_scan_mfma<<<512, 1024, 0, stream>>>(x, Wb, bias, Pc, Sc);
  combine_kernel<<<64, 128, 0, stream>>>(Pc, Sc, out);
}